// Round 2
// baseline (233.329 us; speedup 1.0000x reference)
//
#include <hip/hip_runtime.h>
#include <stdint.h>

// Problem constants (fixed by the reference)
#define TSEQ 4096
#define CEMB 1024
#define DH   64
#define NB   4

typedef __attribute__((ext_vector_type(8))) short bf16x8;  // 8 bf16 (4 VGPRs) MFMA frag
typedef __attribute__((ext_vector_type(4))) float f32x4;   // MFMA accum frag
typedef __attribute__((ext_vector_type(4))) float f4;
typedef unsigned short u16;

// fp32 -> bf16 round-to-nearest-even
__device__ __forceinline__ u16 f2bf(float f) {
  union { float f; uint32_t u; } c; c.f = f;
  uint32_t u = c.u;
  u += 0x7fffu + ((u >> 16) & 1u);
  return (u16)(u >> 16);
}

// XOR-swizzled byte offset inside an LDS tile with 128-byte rows (64 bf16/row).
// Readers and writers both use this -> self-consistent. Kills the 16-way
// bank conflict of row-major [R][64]bf16 ds_read_b128.
__device__ __forceinline__ int swz(int row, int colbyte) {
  return row * 128 + (colbyte ^ ((row & 7) << 4));
}

// ---------------------------------------------------------------------------
// prep: W[1024][64] fp32 (q,k,v) -> wt[3][64][1024] bf16 (transposed)
// ---------------------------------------------------------------------------
__global__ void prep_w(const float* __restrict__ Wq, const float* __restrict__ Wk,
                       const float* __restrict__ Wv, u16* __restrict__ wt) {
  int idx = blockIdx.x * 256 + threadIdx.x;
  if (idx >= 3 * DH * CEMB) return;
  int m = idx >> 16;            // which matrix
  int n = (idx >> 10) & 63;     // head dim
  int k = idx & 1023;           // embed dim
  const float* W = (m == 0) ? Wq : (m == 1) ? Wk : Wv;
  wt[idx] = f2bf(W[k * DH + n]);
}

// ---------------------------------------------------------------------------
// QKV projection GEMM: C[16384 x 64] = X[16384 x 1024] @ W, one of q/k/v per
// blockIdx.y. BM=128 BN=64 BK=64, 4 waves x (32 rows x 64 cols) each.
// fp32->bf16 conversion fused into X staging. RoPE fused into epilogue for
// q/k; v stored transposed vt[b][d][t] for the attention PV step.
// ---------------------------------------------------------------------------
__launch_bounds__(256)
__global__ void qkv_gemm(const float* __restrict__ x, const u16* __restrict__ wt,
                         const float* __restrict__ fc, const float* __restrict__ fs,
                         u16* __restrict__ q_ws, u16* __restrict__ k_ws,
                         u16* __restrict__ vt_ws) {
  __shared__ __align__(16) u16 xs[128 * 64];   // X tile, swizzled
  __shared__ __align__(16) u16 wsh[64 * 64];   // Wt tile [n][k], swizzled

  const int tid  = threadIdx.x;
  const int lane = tid & 63;
  const int w    = tid >> 6;
  const int l15  = lane & 15;
  const int lhi  = lane >> 4;
  const int mat  = blockIdx.y;            // 0=q 1=k 2=v
  const int m0   = blockIdx.x * 128;

  const f32x4 z4 = {0.f, 0.f, 0.f, 0.f};
  f32x4 acc[2][4];
#pragma unroll
  for (int i = 0; i < 2; ++i)
#pragma unroll
    for (int j = 0; j < 4; ++j) acc[i][j] = z4;

  for (int k0 = 0; k0 < CEMB; k0 += 64) {
    __syncthreads();
    // stage X tile 128x64: fp32 load, convert, swizzled ds_write_b128
#pragma unroll
    for (int it = 0; it < 4; ++it) {
      int g = it * 256 + tid;             // granule = 8 bf16
      int row = g >> 3, c = g & 7;
      const float* src = x + (size_t)(m0 + row) * CEMB + k0 + c * 8;
      f4 a = *(const f4*)src;
      f4 b = *(const f4*)(src + 4);
      bf16x8 v;
      v[0] = (short)f2bf(a[0]); v[1] = (short)f2bf(a[1]);
      v[2] = (short)f2bf(a[2]); v[3] = (short)f2bf(a[3]);
      v[4] = (short)f2bf(b[0]); v[5] = (short)f2bf(b[1]);
      v[6] = (short)f2bf(b[2]); v[7] = (short)f2bf(b[3]);
      *(bf16x8*)((char*)xs + swz(row, c << 4)) = v;
    }
    // stage Wt tile 64x64 (already bf16)
#pragma unroll
    for (int it = 0; it < 2; ++it) {
      int g = it * 256 + tid;
      int n = g >> 3, c = g & 7;
      bf16x8 v = *(const bf16x8*)(wt + (size_t)mat * DH * CEMB + n * CEMB + k0 + c * 8);
      *(bf16x8*)((char*)wsh + swz(n, c << 4)) = v;
    }
    __syncthreads();
    // compute: 16 MFMA per wave per K-step
#pragma unroll
    for (int kk = 0; kk < 2; ++kk) {
      bf16x8 af[2], bfr[4];
#pragma unroll
      for (int mr = 0; mr < 2; ++mr) {
        int row = w * 32 + mr * 16 + l15;
        af[mr] = *(const bf16x8*)((char*)xs + swz(row, (kk * 32 + lhi * 8) * 2));
      }
#pragma unroll
      for (int nc = 0; nc < 4; ++nc) {
        int row = nc * 16 + l15;
        bfr[nc] = *(const bf16x8*)((char*)wsh + swz(row, (kk * 32 + lhi * 8) * 2));
      }
#pragma unroll
      for (int mr = 0; mr < 2; ++mr)
#pragma unroll
        for (int nc = 0; nc < 4; ++nc)
          acc[mr][nc] = __builtin_amdgcn_mfma_f32_16x16x32_bf16(af[mr], bfr[nc], acc[mr][nc], 0, 0, 0);
    }
  }

  // epilogue: D row = (lane>>4)*4 + r, col = lane&15 (guide-verified layout)
#pragma unroll
  for (int mr = 0; mr < 2; ++mr) {
#pragma unroll
    for (int nc = 0; nc < 4; ++nc) {
#pragma unroll
      for (int r = 0; r < 4; ++r) {
        float v = acc[mr][nc][r];
        float o = __shfl_xor(v, 1);               // RoPE pair partner (adjacent col)
        int row = m0 + w * 32 + mr * 16 + lhi * 4 + r;
        int col = nc * 16 + l15;
        if (mat == 2) {
          int b = row >> 12, t = row & 4095;
          vt_ws[((size_t)(b * DH + col)) * TSEQ + t] = f2bf(v);
        } else {
          int t = row & 4095;
          int p = col >> 1;
          float cv = fc[t * 32 + p], sv = fs[t * 32 + p];
          float outv = ((col & 1) == 0) ? (v * cv - o * sv)   // real part
                                        : (o * sv + v * cv);  // imag part
          u16* dst = (mat == 0) ? q_ws : k_ws;
          dst[(size_t)row * DH + col] = f2bf(outv);
        }
      }
    }
  }
}

// ---------------------------------------------------------------------------
// Flash attention, causal. QBLK=64 (4 waves x 16 q-rows), KVBLK=64.
// Q frags in registers; K tile + V^T tile in swizzled LDS; P bounced through
// padded per-wave LDS (same-wave, no barrier). Online softmax in D-layout.
// ---------------------------------------------------------------------------
__launch_bounds__(256)
__global__ void attn(const u16* __restrict__ q_ws, const u16* __restrict__ k_ws,
                     const u16* __restrict__ vt_ws, float* __restrict__ out) {
  __shared__ __align__(16) u16 kt[64 * 64];      // K tile [kv][d], swizzled
  __shared__ __align__(16) u16 vts[64 * 64];     // V^T tile [d][kv], swizzled
  __shared__ __align__(16) u16 pt[4][16 * 72];   // per-wave P [qr][kv], +8 pad

  const int tid  = threadIdx.x;
  const int lane = tid & 63;
  const int w    = tid >> 6;
  const int l15  = lane & 15;
  const int lhi  = lane >> 4;
  const int b    = blockIdx.y;
  const int q0   = blockIdx.x * 64;

  const u16* qb = q_ws + (size_t)b * TSEQ * DH;
  const u16* kb = k_ws + (size_t)b * TSEQ * DH;
  const u16* vb = vt_ws + (size_t)b * DH * TSEQ;

  // Q fragments (A operand, rows = this wave's 16 q-rows)
  bf16x8 aq[2];
  {
    int qrow = q0 + w * 16 + l15;
#pragma unroll
    for (int kk = 0; kk < 2; ++kk)
      aq[kk] = *(const bf16x8*)(qb + (size_t)qrow * DH + kk * 32 + lhi * 8);
  }

  const f32x4 z4 = {0.f, 0.f, 0.f, 0.f};
  f32x4 oacc[4] = {z4, z4, z4, z4};
  float m_r[4], l_r[4];
#pragma unroll
  for (int r = 0; r < 4; ++r) { m_r[r] = -1e30f; l_r[r] = 0.f; }

  const int myqbase  = q0 + w * 16 + lhi * 4;   // + r = this lane's q rows
  const int wave_max = q0 + w * 16 + 15;
  const int nkv      = blockIdx.x + 1;          // causal: kv tiles 0..q-tile

  for (int kv = 0; kv < nkv; ++kv) {
    const int kv0 = kv * 64;
    __syncthreads();
    // cooperative stage: K tile (linear in k_ws) + V^T tile (row stride TSEQ)
#pragma unroll
    for (int it = 0; it < 2; ++it) {
      int g = it * 256 + tid;
      int row = g >> 3, c = g & 7;
      bf16x8 vk = *(const bf16x8*)(kb + (size_t)(kv0 + row) * DH + c * 8);
      *(bf16x8*)((char*)kt + swz(row, c << 4)) = vk;
      bf16x8 vv = *(const bf16x8*)(vb + (size_t)row * TSEQ + kv0 + c * 8);
      *(bf16x8*)((char*)vts + swz(row, c << 4)) = vv;
    }
    __syncthreads();

    if (kv0 <= wave_max) {               // wave-uniform early-out (fully masked)
      // ---- S = Q K^T (16 x 64 per wave) ----
      f32x4 sacc[4] = {z4, z4, z4, z4};
#pragma unroll
      for (int kk = 0; kk < 2; ++kk) {
#pragma unroll
        for (int cb = 0; cb < 4; ++cb) {
          bf16x8 bk = *(const bf16x8*)((char*)kt + swz(cb * 16 + l15, (kk * 32 + lhi * 8) * 2));
          sacc[cb] = __builtin_amdgcn_mfma_f32_16x16x32_bf16(aq[kk], bk, sacc[cb], 0, 0, 0);
        }
      }
      // ---- scale + causal mask ----
#pragma unroll
      for (int cb = 0; cb < 4; ++cb)
#pragma unroll
        for (int r = 0; r < 4; ++r) {
          int ki = kv0 + cb * 16 + l15;
          int qi = myqbase + r;
          float sv = sacc[cb][r] * 0.125f;
          sacc[cb][r] = (ki <= qi) ? sv : -1e30f;
        }
      // ---- online softmax: row max over 4 col-tiles + 16 lanes ----
      float mx[4];
#pragma unroll
      for (int r = 0; r < 4; ++r)
        mx[r] = fmaxf(fmaxf(sacc[0][r], sacc[1][r]), fmaxf(sacc[2][r], sacc[3][r]));
#pragma unroll
      for (int s = 1; s <= 8; s <<= 1)
#pragma unroll
        for (int r = 0; r < 4; ++r) mx[r] = fmaxf(mx[r], __shfl_xor(mx[r], s));
      float fac[4];
#pragma unroll
      for (int r = 0; r < 4; ++r) {
        float mn = fmaxf(m_r[r], mx[r]);
        fac[r] = __expf(m_r[r] - mn);
        m_r[r] = mn;
      }
      float rs[4] = {0.f, 0.f, 0.f, 0.f};
#pragma unroll
      for (int cb = 0; cb < 4; ++cb)
#pragma unroll
        for (int r = 0; r < 4; ++r) {
          float p = __expf(sacc[cb][r] - m_r[r]);
          sacc[cb][r] = p;
          rs[r] += p;
        }
#pragma unroll
      for (int s = 1; s <= 8; s <<= 1)
#pragma unroll
        for (int r = 0; r < 4; ++r) rs[r] += __shfl_xor(rs[r], s);
#pragma unroll
      for (int r = 0; r < 4; ++r) l_r[r] = l_r[r] * fac[r] + rs[r];
#pragma unroll
      for (int nc = 0; nc < 4; ++nc)
#pragma unroll
        for (int r = 0; r < 4; ++r) oacc[nc][r] *= fac[r];
      // ---- P -> bf16 via per-wave LDS (D-layout write, A-layout read) ----
#pragma unroll
      for (int cb = 0; cb < 4; ++cb)
#pragma unroll
        for (int r = 0; r < 4; ++r)
          pt[w][(lhi * 4 + r) * 72 + cb * 16 + l15] = f2bf(sacc[cb][r]);
      bf16x8 ap[2];
#pragma unroll
      for (int kk = 0; kk < 2; ++kk)
        ap[kk] = *(const bf16x8*)(&pt[w][l15 * 72 + kk * 32 + lhi * 8]);
      // ---- O += P V ----
#pragma unroll
      for (int kk = 0; kk < 2; ++kk)
#pragma unroll
        for (int nc = 0; nc < 4; ++nc) {
          bf16x8 bv = *(const bf16x8*)((char*)vts + swz(nc * 16 + l15, (kk * 32 + lhi * 8) * 2));
          oacc[nc] = __builtin_amdgcn_mfma_f32_16x16x32_bf16(ap[kk], bv, oacc[nc], 0, 0, 0);
        }
    }
  }

  // epilogue: out[b][q][d] = O / l
#pragma unroll
  for (int nc = 0; nc < 4; ++nc)
#pragma unroll
    for (int r = 0; r < 4; ++r) {
      int row = q0 + w * 16 + lhi * 4 + r;
      out[((size_t)b * TSEQ + row) * DH + nc * 16 + l15] = oacc[nc][r] / l_r[r];
    }
}

// ---------------------------------------------------------------------------
extern "C" void kernel_launch(void* const* d_in, const int* in_sizes, int n_in,
                              void* d_out, int out_size, void* d_ws, size_t ws_size,
                              hipStream_t stream) {
  const float* x  = (const float*)d_in[0];
  const float* Wq = (const float*)d_in[1];
  const float* Wk = (const float*)d_in[2];
  const float* Wv = (const float*)d_in[3];
  const float* fc = (const float*)d_in[4];
  const float* fs = (const float*)d_in[5];
  float* out = (float*)d_out;

  // workspace layout (needs ~6.5 MB):
  char* ws = (char*)d_ws;
  u16* wt    = (u16*)(ws);                                  // 384 KB
  u16* q_ws  = (u16*)(ws + (1u << 19));                     // 2 MB
  u16* k_ws  = (u16*)(ws + (1u << 19) + (1u << 21));        // 2 MB
  u16* vt_ws = (u16*)(ws + (1u << 19) + (2u << 21));        // 2 MB

  prep_w<<<(3 * DH * CEMB + 255) / 256, 256, 0, stream>>>(Wq, Wk, Wv, wt);
  qkv_gemm<<<dim3(128, 3), 256, 0, stream>>>(x, wt, fc, fs, q_ws, k_ws, vt_ws);
  attn<<<dim3(TSEQ / 64, NB), 256, 0, stream>>>(q_ws, k_ws, vt_ws, out);
}

// Round 6
// 187.528 us; speedup vs baseline: 1.2442x; 1.2442x over previous
//
#include <hip/hip_runtime.h>
#include <stdint.h>

// Problem constants (fixed by the reference)
#define TSEQ 4096
#define CEMB 1024
#define DH   64
#define NB   4
#define NCHUNK 4      // KV-split factor per q-tile (flash-decoding style)

typedef __attribute__((ext_vector_type(8))) short bf16x8;  // 8 bf16 (4 VGPRs) MFMA frag
typedef __attribute__((ext_vector_type(4))) float f32x4;   // MFMA accum frag
typedef __attribute__((ext_vector_type(4))) float f4;
typedef unsigned short u16;

// fp32 -> bf16 round-to-nearest-even
__device__ __forceinline__ u16 f2bf(float f) {
  union { float f; uint32_t u; } c; c.f = f;
  uint32_t u = c.u;
  u += 0x7fffu + ((u >> 16) & 1u);
  return (u16)(u >> 16);
}

// XOR-swizzled byte offset inside an LDS tile with 128-byte rows (64 bf16/row).
__device__ __forceinline__ int swz(int row, int colbyte) {
  return row * 128 + (colbyte ^ ((row & 7) << 4));
}

// ---------------------------------------------------------------------------
// prep: W[1024][64] fp32 (q,k,v) -> wt[3*64][1024] bf16 (transposed)
// ---------------------------------------------------------------------------
__global__ void prep_w(const float* __restrict__ Wq, const float* __restrict__ Wk,
                       const float* __restrict__ Wv, u16* __restrict__ wt) {
  int idx = blockIdx.x * 256 + threadIdx.x;
  if (idx >= 3 * DH * CEMB) return;
  int m = idx >> 16;            // which matrix
  int n = (idx >> 10) & 63;     // head dim
  int k = idx & 1023;           // embed dim
  const float* W = (m == 0) ? Wq : (m == 1) ? Wk : Wv;
  wt[idx] = f2bf(W[k * DH + n]);
}

// ---------------------------------------------------------------------------
// Fused QKV projection GEMM: one block computes q,k,v for a 64-row X slice.
// C[64 x 192] = X[64 x 1024] @ Wt^T. BM=64 BN=192 BK=64, 4 waves x 16 rows,
// each wave covers all 192 output cols (12 n-frags). X read ONCE from HBM.
// RoPE fused into epilogue for q/k; v stored transposed vt[b][d][t].
// ---------------------------------------------------------------------------
__launch_bounds__(256)
__global__ void qkv_gemm(const float* __restrict__ x, const u16* __restrict__ wt,
                         const float* __restrict__ fc, const float* __restrict__ fs,
                         u16* __restrict__ q_ws, u16* __restrict__ k_ws,
                         u16* __restrict__ vt_ws) {
  __shared__ __align__(16) u16 xs[64 * 64];     // X tile, swizzled
  __shared__ __align__(16) u16 wsh[192 * 64];   // Wt tile [n(=mat*64+d)][k], swizzled

  const int tid  = threadIdx.x;
  const int lane = tid & 63;
  const int w    = tid >> 6;
  const int l15  = lane & 15;
  const int lhi  = lane >> 4;
  const int m0   = blockIdx.x * 64;

  const f32x4 z4 = {0.f, 0.f, 0.f, 0.f};
  f32x4 acc[12];
#pragma unroll
  for (int j = 0; j < 12; ++j) acc[j] = z4;

  for (int k0 = 0; k0 < CEMB; k0 += 64) {
    __syncthreads();
    // stage X tile 64x64: fp32 load, convert, swizzled ds_write_b128
#pragma unroll
    for (int it = 0; it < 2; ++it) {
      int g = it * 256 + tid;             // granule = 8 bf16
      int row = g >> 3, c = g & 7;
      const float* src = x + (size_t)(m0 + row) * CEMB + k0 + c * 8;
      f4 a = *(const f4*)src;
      f4 b = *(const f4*)(src + 4);
      bf16x8 v;
      v[0] = (short)f2bf(a[0]); v[1] = (short)f2bf(a[1]);
      v[2] = (short)f2bf(a[2]); v[3] = (short)f2bf(a[3]);
      v[4] = (short)f2bf(b[0]); v[5] = (short)f2bf(b[1]);
      v[6] = (short)f2bf(b[2]); v[7] = (short)f2bf(b[3]);
      *(bf16x8*)((char*)xs + swz(row, c << 4)) = v;
    }
    // stage Wt tile 192x64 (bf16, L2-resident)
#pragma unroll
    for (int it = 0; it < 6; ++it) {
      int g = it * 256 + tid;
      int n = g >> 3, c = g & 7;
      bf16x8 v = *(const bf16x8*)(wt + (size_t)n * CEMB + k0 + c * 8);
      *(bf16x8*)((char*)wsh + swz(n, c << 4)) = v;
    }
    __syncthreads();
    // compute: 24 MFMA per wave per K-step
#pragma unroll
    for (int kk = 0; kk < 2; ++kk) {
      bf16x8 af = *(const bf16x8*)((char*)xs + swz(w * 16 + l15, (kk * 32 + lhi * 8) * 2));
#pragma unroll
      for (int nc = 0; nc < 12; ++nc) {
        bf16x8 bfr = *(const bf16x8*)((char*)wsh + swz(nc * 16 + l15, (kk * 32 + lhi * 8) * 2));
        acc[nc] = __builtin_amdgcn_mfma_f32_16x16x32_bf16(af, bfr, acc[nc], 0, 0, 0);
      }
    }
  }

  // epilogue: D row = (lane>>4)*4 + r, col = lane&15
#pragma unroll
  for (int nc = 0; nc < 12; ++nc) {
    int mat = nc >> 2;                    // 0=q 1=k 2=v
    int col = (nc & 3) * 16 + l15;        // head dim 0..63
#pragma unroll
    for (int r = 0; r < 4; ++r) {
      float v = acc[nc][r];
      float o = __shfl_xor(v, 1);         // RoPE pair partner (adjacent col)
      int row = m0 + w * 16 + lhi * 4 + r;
      int b = row >> 12, t = row & 4095;
      if (mat == 2) {
        vt_ws[((size_t)(b * DH + col)) * TSEQ + t] = f2bf(v);
      } else {
        int p = col >> 1;
        float cv = fc[t * 32 + p], sv = fs[t * 32 + p];
        float outv = ((col & 1) == 0) ? (v * cv - o * sv)   // real part
                                      : (o * sv + v * cv);  // imag part
        u16* dst = (mat == 0) ? q_ws : k_ws;
        dst[(size_t)row * DH + col] = f2bf(outv);
      }
    }
  }
}

// ---------------------------------------------------------------------------
// Flash attention partials, causal, KV-chunked. QBLK=64 (4 waves x 16 rows),
// KVBLK=64. Block (qt, b, c) handles chunk c of q-tile qt's KV range and
// writes partial (O f32, m, l) to workspace. Grid 64 x 4 x 4.
// ---------------------------------------------------------------------------
__launch_bounds__(256)
__global__ void attn_partial(const u16* __restrict__ q_ws, const u16* __restrict__ k_ws,
                             const u16* __restrict__ vt_ws, float* __restrict__ po,
                             float* __restrict__ pml) {
  const int qt = blockIdx.x;
  const int b  = blockIdx.y;
  const int c  = blockIdx.z;

  const int ntiles = qt + 1;                    // causal KV-tiles for this qtile
  const int cnt    = (ntiles + NCHUNK - 1) / NCHUNK;
  const int t0     = c * cnt;
  if (t0 >= ntiles) return;                     // dead chunk (uniform exit, pre-barrier)
  const int t1     = min(t0 + cnt, ntiles);

  __shared__ __align__(16) u16 kt[64 * 64];      // K tile [kv][d], swizzled
  __shared__ __align__(16) u16 vts[64 * 64];     // V^T tile [d][kv], swizzled
  __shared__ __align__(16) u16 pt[4][16 * 72];   // per-wave P [qr][kv], +8 pad

  const int tid  = threadIdx.x;
  const int lane = tid & 63;
  const int w    = tid >> 6;
  const int l15  = lane & 15;
  const int lhi  = lane >> 4;
  const int q0   = qt * 64;

  const u16* qb = q_ws + (size_t)b * TSEQ * DH;
  const u16* kb = k_ws + (size_t)b * TSEQ * DH;
  const u16* vb = vt_ws + (size_t)b * DH * TSEQ;

  // Q fragments (A operand, rows = this wave's 16 q-rows)
  bf16x8 aq[2];
  {
    int qrow = q0 + w * 16 + l15;
#pragma unroll
    for (int kk = 0; kk < 2; ++kk)
      aq[kk] = *(const bf16x8*)(qb + (size_t)qrow * DH + kk * 32 + lhi * 8);
  }

  const f32x4 z4 = {0.f, 0.f, 0.f, 0.f};
  f32x4 oacc[4] = {z4, z4, z4, z4};
  float m_r[4], l_r[4];
#pragma unroll
  for (int r = 0; r < 4; ++r) { m_r[r] = -1e30f; l_r[r] = 0.f; }

  const int myqbase = q0 + w * 16 + lhi * 4;    // + r = this lane's q rows

  for (int kv = t0; kv < t1; ++kv) {
    const int kv0 = kv * 64;
    __syncthreads();
    // cooperative stage: K tile (linear) + V^T tile (row stride TSEQ)
#pragma unroll
    for (int it = 0; it < 2; ++it) {
      int g = it * 256 + tid;
      int row = g >> 3, cc = g & 7;
      bf16x8 vk = *(const bf16x8*)(kb + (size_t)(kv0 + row) * DH + cc * 8);
      *(bf16x8*)((char*)kt + swz(row, cc << 4)) = vk;
      bf16x8 vv = *(const bf16x8*)(vb + (size_t)row * TSEQ + kv0 + cc * 8);
      *(bf16x8*)((char*)vts + swz(row, cc << 4)) = vv;
    }
    __syncthreads();

    // ---- S = Q K^T (16 x 64 per wave) ----
    f32x4 sacc[4] = {z4, z4, z4, z4};
#pragma unroll
    for (int kk = 0; kk < 2; ++kk) {
#pragma unroll
      for (int cb = 0; cb < 4; ++cb) {
        bf16x8 bk = *(const bf16x8*)((char*)kt + swz(cb * 16 + l15, (kk * 32 + lhi * 8) * 2));
        sacc[cb] = __builtin_amdgcn_mfma_f32_16x16x32_bf16(aq[kk], bk, sacc[cb], 0, 0, 0);
      }
    }
    // ---- scale + causal mask ----
#pragma unroll
    for (int cb = 0; cb < 4; ++cb)
#pragma unroll
      for (int r = 0; r < 4; ++r) {
        int ki = kv0 + cb * 16 + l15;
        int qi = myqbase + r;
        float sv = sacc[cb][r] * 0.125f;
        sacc[cb][r] = (ki <= qi) ? sv : -1e30f;
      }
    // ---- online softmax ----
    float mx[4];
#pragma unroll
    for (int r = 0; r < 4; ++r)
      mx[r] = fmaxf(fmaxf(sacc[0][r], sacc[1][r]), fmaxf(sacc[2][r], sacc[3][r]));
#pragma unroll
    for (int s = 1; s <= 8; s <<= 1)
#pragma unroll
      for (int r = 0; r < 4; ++r) mx[r] = fmaxf(mx[r], __shfl_xor(mx[r], s));
    float fac[4];
#pragma unroll
    for (int r = 0; r < 4; ++r) {
      float mn = fmaxf(m_r[r], mx[r]);
      fac[r] = __expf(m_r[r] - mn);
      m_r[r] = mn;
    }
    float rs[4] = {0.f, 0.f, 0.f, 0.f};
#pragma unroll
    for (int cb = 0; cb < 4; ++cb)
#pragma unroll
      for (int r = 0; r < 4; ++r) {
        float p = __expf(sacc[cb][r] - m_r[r]);
        sacc[cb][r] = p;
        rs[r] += p;
      }
#pragma unroll
    for (int s = 1; s <= 8; s <<= 1)
#pragma unroll
      for (int r = 0; r < 4; ++r) rs[r] += __shfl_xor(rs[r], s);
#pragma unroll
    for (int r = 0; r < 4; ++r) l_r[r] = l_r[r] * fac[r] + rs[r];
#pragma unroll
    for (int nc = 0; nc < 4; ++nc)
#pragma unroll
      for (int r = 0; r < 4; ++r) oacc[nc][r] *= fac[r];
    // ---- P -> bf16 via per-wave LDS (D-layout write, A-layout read) ----
#pragma unroll
    for (int cb = 0; cb < 4; ++cb)
#pragma unroll
      for (int r = 0; r < 4; ++r)
        pt[w][(lhi * 4 + r) * 72 + cb * 16 + l15] = f2bf(sacc[cb][r]);
    bf16x8 ap[2];
#pragma unroll
    for (int kk = 0; kk < 2; ++kk)
      ap[kk] = *(const bf16x8*)(&pt[w][l15 * 72 + kk * 32 + lhi * 8]);
    // ---- O += P V ----
#pragma unroll
    for (int kk = 0; kk < 2; ++kk)
#pragma unroll
      for (int nc = 0; nc < 4; ++nc) {
        bf16x8 bv = *(const bf16x8*)((char*)vts + swz(nc * 16 + l15, (kk * 32 + lhi * 8) * 2));
        oacc[nc] = __builtin_amdgcn_mfma_f32_16x16x32_bf16(ap[kk], bv, oacc[nc], 0, 0, 0);
      }
  }

  // write partial: O (no div), m, l
  const int slot = ((b * 64 + qt) * NCHUNK + c);
  float* o_out = po + (size_t)slot * (64 * 64);
#pragma unroll
  for (int nc = 0; nc < 4; ++nc)
#pragma unroll
    for (int r = 0; r < 4; ++r) {
      int rloc = w * 16 + lhi * 4 + r;
      o_out[rloc * 64 + nc * 16 + l15] = oacc[nc][r];
    }
#pragma unroll
  for (int r = 0; r < 4; ++r) {
    if (l15 == 0) {                        // one writer per row
      int rloc = w * 16 + lhi * 4 + r;
      pml[(size_t)slot * 128 + rloc]      = m_r[r];
      pml[(size_t)slot * 128 + 64 + rloc] = l_r[r];
    }
  }
}

// ---------------------------------------------------------------------------
// Combine partials: out[b][t][d] = sum_c e^{m_c-M} O_c[d] / sum_c e^{m_c-M} l_c
// ---------------------------------------------------------------------------
__launch_bounds__(256)
__global__ void attn_combine(const float* __restrict__ po, const float* __restrict__ pml,
                             float* __restrict__ out) {
  int idx = blockIdx.x * 256 + threadIdx.x;    // idx over B*T*DH = 1M
  int d   = idx & 63;
  int t   = (idx >> 6) & 4095;
  int b   = idx >> 18;
  int qt  = t >> 6;
  int rloc = t & 63;
  int ntiles = qt + 1;
  int cnt = (ntiles + NCHUNK - 1) / NCHUNK;

  float m_c[NCHUNK], l_c[NCHUNK], o_c[NCHUNK];
  float M = -1e30f;
#pragma unroll
  for (int c = 0; c < NCHUNK; ++c) {
    bool valid = (c * cnt < ntiles);
    int slot = ((b * 64 + qt) * NCHUNK + c);
    m_c[c] = valid ? pml[(size_t)slot * 128 + rloc]      : -1e30f;
    l_c[c] = valid ? pml[(size_t)slot * 128 + 64 + rloc] : 0.f;
    o_c[c] = valid ? po[(size_t)slot * (64 * 64) + rloc * 64 + d] : 0.f;
    M = fmaxf(M, m_c[c]);
  }
  float den = 0.f, num = 0.f;
#pragma unroll
  for (int c = 0; c < NCHUNK; ++c) {
    float e = __expf(m_c[c] - M);
    den += e * l_c[c];
    num += e * o_c[c];
  }
  out[idx] = num / den;
}

// ---------------------------------------------------------------------------
extern "C" void kernel_launch(void* const* d_in, const int* in_sizes, int n_in,
                              void* d_out, int out_size, void* d_ws, size_t ws_size,
                              hipStream_t stream) {
  const float* x  = (const float*)d_in[0];
  const float* Wq = (const float*)d_in[1];
  const float* Wk = (const float*)d_in[2];
  const float* Wv = (const float*)d_in[3];
  const float* fc = (const float*)d_in[4];
  const float* fs = (const float*)d_in[5];
  float* out = (float*)d_out;

  // workspace layout (~23 MB):
  char* ws = (char*)d_ws;
  u16*   wt    = (u16*)(ws);                                   // 384 KB (pad 512K)
  u16*   q_ws  = (u16*)(ws + (1u << 19));                      // 2 MB
  u16*   k_ws  = (u16*)(ws + (1u << 19) + (1u << 21));         // 2 MB
  u16*   vt_ws = (u16*)(ws + (1u << 19) + (2u << 21));         // 2 MB
  float* po    = (float*)(ws + (1u << 19) + (3u << 21));       // 1024*4096*4 = 16 MB
  float* pml   = (float*)(ws + (1u << 19) + (3u << 21) + (1u << 24)); // 512 KB

  prep_w<<<(3 * DH * CEMB + 255) / 256, 256, 0, stream>>>(Wq, Wk, Wv, wt);
  qkv_gemm<<<dim3(256), 256, 0, stream>>>(x, wt, fc, fs, q_ws, k_ws, vt_ws);
  attn_partial<<<dim3(64, NB, NCHUNK), 256, 0, stream>>>(q_ws, k_ws, vt_ws, po, pml);
  attn_combine<<<dim3((NB * TSEQ * DH) / 256), 256, 0, stream>>>(po, pml, out);
}

// Round 7
// 180.382 us; speedup vs baseline: 1.2935x; 1.0396x over previous
//
#include <hip/hip_runtime.h>
#include <stdint.h>

// Problem constants (fixed by the reference)
#define TSEQ 4096
#define CEMB 1024
#define DH   64
#define NB   4
#define NCHUNK 4      // KV-split factor per q-tile (flash-decoding style)

typedef __attribute__((ext_vector_type(8))) short bf16x8;  // 8 bf16 (4 VGPRs) MFMA frag
typedef __attribute__((ext_vector_type(4))) float f32x4;   // MFMA accum frag
typedef __attribute__((ext_vector_type(4))) float f4;
typedef unsigned short u16;

// fp32 -> bf16 round-to-nearest-even
__device__ __forceinline__ u16 f2bf(float f) {
  union { float f; uint32_t u; } c; c.f = f;
  uint32_t u = c.u;
  u += 0x7fffu + ((u >> 16) & 1u);
  return (u16)(u >> 16);
}

// XOR-swizzled byte offset inside an LDS tile with 128-byte rows (64 bf16/row).
__device__ __forceinline__ int swz(int row, int colbyte) {
  return row * 128 + (colbyte ^ ((row & 7) << 4));
}

// ---------------------------------------------------------------------------
// prep: W[1024][64] fp32 (q,k,v) -> wt[3*64][1024] bf16 (transposed).
// Reads coalesced (idx walks W row-major); writes scattered (stores don't stall).
// ---------------------------------------------------------------------------
__global__ void prep_w(const float* __restrict__ Wq, const float* __restrict__ Wk,
                       const float* __restrict__ Wv, u16* __restrict__ wt) {
  int idx = blockIdx.x * 256 + threadIdx.x;
  if (idx >= 3 * DH * CEMB) return;
  int m = idx >> 16;            // which matrix
  int r = idx & 65535;          // index into W (row-major [k][n])
  int k = r >> 6, n = r & 63;
  const float* W = (m == 0) ? Wq : (m == 1) ? Wk : Wv;
  wt[(size_t)m * 65536 + n * 1024 + k] = f2bf(W[r]);
}

// ---------------------------------------------------------------------------
// Fused QKV projection GEMM: C[32 x 192] = X[32 x 1024] @ Wt^T per block.
// BM=32 (grid 512 = 2 blocks/CU), BK=64, 4 waves = 2 row-groups x 2 col-groups
// (each wave: 16 rows x 96 cols = 6 n-frags). Double-buffered LDS staging with
// async issue-early/write-late. fp32->bf16 conversion fused into X staging.
// RoPE fused into epilogue for q/k; v stored transposed vt[b][d][t].
// ---------------------------------------------------------------------------
#define QKV_LOADX(K0) { \
    const float* s_ = x + (size_t)(m0 + xrow) * CEMB + (K0) + xc * 8; \
    xa = *(const f4*)s_; xb = *(const f4*)(s_ + 4); }
#define QKV_LOADW(K0) \
    _Pragma("unroll") for (int it = 0; it < 6; ++it) { \
      int gg = it * 256 + tid; \
      wv[it] = *(const bf16x8*)(wt + (size_t)(gg >> 3) * CEMB + (K0) + (gg & 7) * 8); }
#define QKV_STORE(BUF) { \
    bf16x8 xv_; \
    xv_[0] = (short)f2bf(xa[0]); xv_[1] = (short)f2bf(xa[1]); \
    xv_[2] = (short)f2bf(xa[2]); xv_[3] = (short)f2bf(xa[3]); \
    xv_[4] = (short)f2bf(xb[0]); xv_[5] = (short)f2bf(xb[1]); \
    xv_[6] = (short)f2bf(xb[2]); xv_[7] = (short)f2bf(xb[3]); \
    *(bf16x8*)((char*)xs[BUF] + swz(xrow, xc << 4)) = xv_; \
    _Pragma("unroll") for (int it = 0; it < 6; ++it) { \
      int gg = it * 256 + tid; \
      *(bf16x8*)((char*)wsh[BUF] + swz(gg >> 3, (gg & 7) << 4)) = wv[it]; } }

__launch_bounds__(256)
__global__ void qkv_gemm(const float* __restrict__ x, const u16* __restrict__ wt,
                         const float* __restrict__ fc, const float* __restrict__ fs,
                         u16* __restrict__ q_ws, u16* __restrict__ k_ws,
                         u16* __restrict__ vt_ws) {
  __shared__ __align__(16) u16 xs[2][32 * 64];    //  8 KB
  __shared__ __align__(16) u16 wsh[2][192 * 64];  // 48 KB

  const int tid  = threadIdx.x;
  const int lane = tid & 63;
  const int w    = tid >> 6;
  const int l15  = lane & 15;
  const int lhi  = lane >> 4;
  const int rg   = w & 1;              // row-group (16 rows)
  const int cg   = w >> 1;             // col-group (96 cols)
  const int m0   = blockIdx.x * 32;
  const int xrow = tid >> 3, xc = tid & 7;   // X staging granule

  const f32x4 z4 = {0.f, 0.f, 0.f, 0.f};
  f32x4 acc[6];
#pragma unroll
  for (int j = 0; j < 6; ++j) acc[j] = z4;

  f4 xa, xb;
  bf16x8 wv[6];

  // prologue: stage k0 = 0 into buffer 0
  QKV_LOADX(0)
  QKV_LOADW(0)
  QKV_STORE(0)
  __syncthreads();

  for (int ks = 0; ks < CEMB / 64; ++ks) {
    const int cur  = ks & 1;
    const bool more = (ks + 1 < CEMB / 64);
    if (more) {                       // issue next tile's loads EARLY
      QKV_LOADX((ks + 1) * 64)
      QKV_LOADW((ks + 1) * 64)
    }
    // compute on current buffer: 12 MFMA per wave
#pragma unroll
    for (int kk = 0; kk < 2; ++kk) {
      bf16x8 af = *(const bf16x8*)((char*)xs[cur] + swz(rg * 16 + l15, (kk * 32 + lhi * 8) * 2));
#pragma unroll
      for (int nc = 0; nc < 6; ++nc) {
        bf16x8 bfr = *(const bf16x8*)((char*)wsh[cur] + swz(cg * 96 + nc * 16 + l15, (kk * 32 + lhi * 8) * 2));
        acc[nc] = __builtin_amdgcn_mfma_f32_16x16x32_bf16(af, bfr, acc[nc], 0, 0, 0);
      }
    }
    if (more) QKV_STORE(cur ^ 1)      // write LATE (latency hidden under MFMA)
    __syncthreads();
  }

  // epilogue: D row = (lane>>4)*4 + r, col = lane&15
#pragma unroll
  for (int nc = 0; nc < 6; ++nc) {
    int gcol = cg * 96 + nc * 16 + l15;   // 0..191
    int mat  = gcol >> 6;                 // 0=q 1=k 2=v
    int col  = gcol & 63;                 // head dim
#pragma unroll
    for (int r = 0; r < 4; ++r) {
      float v = acc[nc][r];
      float o = __shfl_xor(v, 1);         // RoPE pair partner (adjacent col)
      int row = m0 + rg * 16 + lhi * 4 + r;
      int b = row >> 12, t = row & 4095;
      if (mat == 2) {
        vt_ws[((size_t)(b * DH + col)) * TSEQ + t] = f2bf(v);
      } else {
        int p = col >> 1;
        float cv = fc[t * 32 + p], sv = fs[t * 32 + p];
        float outv = ((col & 1) == 0) ? (v * cv - o * sv)   // real part
                                      : (o * sv + v * cv);  // imag part
        u16* dst = (mat == 0) ? q_ws : k_ws;
        dst[(size_t)row * DH + col] = f2bf(outv);
      }
    }
  }
}

// ---------------------------------------------------------------------------
// Flash attention partials, causal, KV-chunked. QBLK=64 (4 waves x 16 rows),
// KVBLK=64. Double-buffered K/V LDS with async issue-early/write-late staging;
// ONE barrier per KV step. Block (qt,b,c) -> partial (O f32, m, l).
// LDS = 16+16+8 = 40 KB -> exactly 4 blocks/CU.
// ---------------------------------------------------------------------------
#define ATT_LOADKV(KV0) \
    _Pragma("unroll") for (int it = 0; it < 2; ++it) { \
      int gg = it * 256 + tid, row_ = gg >> 3, cc_ = gg & 7; \
      kreg[it] = *(const bf16x8*)(kb + (size_t)((KV0) + row_) * DH + cc_ * 8); \
      vreg[it] = *(const bf16x8*)(vb + (size_t)row_ * TSEQ + (KV0) + cc_ * 8); }
#define ATT_WRITEKV(BUF) \
    _Pragma("unroll") for (int it = 0; it < 2; ++it) { \
      int gg = it * 256 + tid, row_ = gg >> 3, cc_ = gg & 7; \
      *(bf16x8*)((char*)kt[BUF] + swz(row_, cc_ << 4)) = kreg[it]; \
      *(bf16x8*)((char*)vts[BUF] + swz(row_, cc_ << 4)) = vreg[it]; }

__launch_bounds__(256)
__global__ void attn_partial(const u16* __restrict__ q_ws, const u16* __restrict__ k_ws,
                             const u16* __restrict__ vt_ws, float* __restrict__ po,
                             float* __restrict__ pml) {
  const int qt = blockIdx.x;
  const int b  = blockIdx.y;
  const int c  = blockIdx.z;

  const int ntiles = qt + 1;                    // causal KV-tiles for this qtile
  const int cnt    = (ntiles + NCHUNK - 1) / NCHUNK;
  const int t0     = c * cnt;
  if (t0 >= ntiles) return;                     // dead chunk (uniform exit, pre-barrier)
  const int t1     = min(t0 + cnt, ntiles);
  const int nst    = t1 - t0;

  __shared__ __align__(16) u16 kt[2][64 * 64];   // K tiles, swizzled (16 KB)
  __shared__ __align__(16) u16 vts[2][64 * 64];  // V^T tiles, swizzled (16 KB)
  __shared__ __align__(16) u16 pt2[4 * 16 * 64]; // per-wave P, swizzled (8 KB)

  const int tid  = threadIdx.x;
  const int lane = tid & 63;
  const int w    = tid >> 6;
  const int l15  = lane & 15;
  const int lhi  = lane >> 4;
  const int q0   = qt * 64;

  const u16* qb = q_ws + (size_t)b * TSEQ * DH;
  const u16* kb = k_ws + (size_t)b * TSEQ * DH;
  const u16* vb = vt_ws + (size_t)b * DH * TSEQ;
  char* ptw = (char*)pt2 + w * 2048;            // this wave's P region

  // Q fragments (A operand, rows = this wave's 16 q-rows)
  bf16x8 aq[2];
  {
    int qrow = q0 + w * 16 + l15;
#pragma unroll
    for (int kk = 0; kk < 2; ++kk)
      aq[kk] = *(const bf16x8*)(qb + (size_t)qrow * DH + kk * 32 + lhi * 8);
  }

  const f32x4 z4 = {0.f, 0.f, 0.f, 0.f};
  f32x4 oacc[4] = {z4, z4, z4, z4};
  float m_r[4], l_r[4];
#pragma unroll
  for (int r = 0; r < 4; ++r) { m_r[r] = -1e30f; l_r[r] = 0.f; }

  const int myqbase = q0 + w * 16 + lhi * 4;    // + r = this lane's q rows

  bf16x8 kreg[2], vreg[2];

  // prologue: stage first tile into buffer 0
  ATT_LOADKV(t0 * 64)
  ATT_WRITEKV(0)
  __syncthreads();

  for (int i = 0; i < nst; ++i) {
    const int kv0 = (t0 + i) * 64;
    const int cur = i & 1;
    const bool more = (i + 1 < nst);
    if (more) ATT_LOADKV((t0 + i + 1) * 64)     // issue next tile EARLY

    // ---- S = Q K^T (16 x 64 per wave) ----
    f32x4 sacc[4] = {z4, z4, z4, z4};
#pragma unroll
    for (int kk = 0; kk < 2; ++kk) {
#pragma unroll
      for (int cb = 0; cb < 4; ++cb) {
        bf16x8 bk = *(const bf16x8*)((char*)kt[cur] + swz(cb * 16 + l15, (kk * 32 + lhi * 8) * 2));
        sacc[cb] = __builtin_amdgcn_mfma_f32_16x16x32_bf16(aq[kk], bk, sacc[cb], 0, 0, 0);
      }
    }
    // ---- scale + causal mask ----
#pragma unroll
    for (int cb = 0; cb < 4; ++cb)
#pragma unroll
      for (int r = 0; r < 4; ++r) {
        int ki = kv0 + cb * 16 + l15;
        int qi = myqbase + r;
        float sv = sacc[cb][r] * 0.125f;
        sacc[cb][r] = (ki <= qi) ? sv : -1e30f;
      }
    // ---- online softmax ----
    float mx[4];
#pragma unroll
    for (int r = 0; r < 4; ++r)
      mx[r] = fmaxf(fmaxf(sacc[0][r], sacc[1][r]), fmaxf(sacc[2][r], sacc[3][r]));
#pragma unroll
    for (int s = 1; s <= 8; s <<= 1)
#pragma unroll
      for (int r = 0; r < 4; ++r) mx[r] = fmaxf(mx[r], __shfl_xor(mx[r], s));
    float fac[4];
#pragma unroll
    for (int r = 0; r < 4; ++r) {
      float mn = fmaxf(m_r[r], mx[r]);
      fac[r] = __expf(m_r[r] - mn);
      m_r[r] = mn;
    }
    float rs[4] = {0.f, 0.f, 0.f, 0.f};
#pragma unroll
    for (int cb = 0; cb < 4; ++cb)
#pragma unroll
      for (int r = 0; r < 4; ++r) {
        float p = __expf(sacc[cb][r] - m_r[r]);
        sacc[cb][r] = p;
        rs[r] += p;
      }
#pragma unroll
    for (int s = 1; s <= 8; s <<= 1)
#pragma unroll
      for (int r = 0; r < 4; ++r) rs[r] += __shfl_xor(rs[r], s);
#pragma unroll
    for (int r = 0; r < 4; ++r) l_r[r] = l_r[r] * fac[r] + rs[r];
#pragma unroll
    for (int nc = 0; nc < 4; ++nc)
#pragma unroll
      for (int r = 0; r < 4; ++r) oacc[nc][r] *= fac[r];
    // ---- P -> bf16 via per-wave swizzled LDS (same wave, no barrier) ----
#pragma unroll
    for (int cb = 0; cb < 4; ++cb)
#pragma unroll
      for (int r = 0; r < 4; ++r)
        *(u16*)(ptw + swz(lhi * 4 + r, (cb * 16 + l15) * 2)) = f2bf(sacc[cb][r]);
    bf16x8 ap[2];
#pragma unroll
    for (int kk = 0; kk < 2; ++kk)
      ap[kk] = *(const bf16x8*)(ptw + swz(l15, (kk * 32 + lhi * 8) * 2));
    // ---- O += P V ----
#pragma unroll
    for (int kk = 0; kk < 2; ++kk)
#pragma unroll
      for (int nc = 0; nc < 4; ++nc) {
        bf16x8 bv = *(const bf16x8*)((char*)vts[cur] + swz(nc * 16 + l15, (kk * 32 + lhi * 8) * 2));
        oacc[nc] = __builtin_amdgcn_mfma_f32_16x16x32_bf16(ap[kk], bv, oacc[nc], 0, 0, 0);
      }

    if (more) ATT_WRITEKV(cur ^ 1)    // write LATE into other buffer
    __syncthreads();                  // one barrier per step
  }

  // write partial: O (no div), m, l
  const int slot = ((b * 64 + qt) * NCHUNK + c);
  float* o_out = po + (size_t)slot * (64 * 64);
#pragma unroll
  for (int nc = 0; nc < 4; ++nc)
#pragma unroll
    for (int r = 0; r < 4; ++r) {
      int rloc = w * 16 + lhi * 4 + r;
      o_out[rloc * 64 + nc * 16 + l15] = oacc[nc][r];
    }
#pragma unroll
  for (int r = 0; r < 4; ++r) {
    if (l15 == 0) {                        // one writer per row
      int rloc = w * 16 + lhi * 4 + r;
      pml[(size_t)slot * 128 + rloc]      = m_r[r];
      pml[(size_t)slot * 128 + 64 + rloc] = l_r[r];
    }
  }
}

// ---------------------------------------------------------------------------
// Combine partials: out[b][t][d] = sum_c e^{m_c-M} O_c[d] / sum_c e^{m_c-M} l_c
// ---------------------------------------------------------------------------
__launch_bounds__(256)
__global__ void attn_combine(const float* __restrict__ po, const float* __restrict__ pml,
                             float* __restrict__ out) {
  int idx = blockIdx.x * 256 + threadIdx.x;    // idx over B*T*DH = 1M
  int d   = idx & 63;
  int t   = (idx >> 6) & 4095;
  int b   = idx >> 18;
  int qt  = t >> 6;
  int rloc = t & 63;
  int ntiles = qt + 1;
  int cnt = (ntiles + NCHUNK - 1) / NCHUNK;

  float m_c[NCHUNK], l_c[NCHUNK], o_c[NCHUNK];
  float M = -1e30f;
#pragma unroll
  for (int c = 0; c < NCHUNK; ++c) {
    bool valid = (c * cnt < ntiles);
    int slot = ((b * 64 + qt) * NCHUNK + c);
    m_c[c] = valid ? pml[(size_t)slot * 128 + rloc]      : -1e30f;
    l_c[c] = valid ? pml[(size_t)slot * 128 + 64 + rloc] : 0.f;
    o_c[c] = valid ? po[(size_t)slot * (64 * 64) + rloc * 64 + d] : 0.f;
    M = fmaxf(M, m_c[c]);
  }
  float den = 0.f, num = 0.f;
#pragma unroll
  for (int c = 0; c < NCHUNK; ++c) {
    float e = __expf(m_c[c] - M);
    den += e * l_c[c];
    num += e * o_c[c];
  }
  out[idx] = num / den;
}

// ---------------------------------------------------------------------------
extern "C" void kernel_launch(void* const* d_in, const int* in_sizes, int n_in,
                              void* d_out, int out_size, void* d_ws, size_t ws_size,
                              hipStream_t stream) {
  const float* x  = (const float*)d_in[0];
  const float* Wq = (const float*)d_in[1];
  const float* Wk = (const float*)d_in[2];
  const float* Wv = (const float*)d_in[3];
  const float* fc = (const float*)d_in[4];
  const float* fs = (const float*)d_in[5];
  float* out = (float*)d_out;

  // workspace layout (~23 MB):
  char* ws = (char*)d_ws;
  u16*   wt    = (u16*)(ws);                                   // 384 KB (pad 512K)
  u16*   q_ws  = (u16*)(ws + (1u << 19));                      // 2 MB
  u16*   k_ws  = (u16*)(ws + (1u << 19) + (1u << 21));         // 2 MB
  u16*   vt_ws = (u16*)(ws + (1u << 19) + (2u << 21));         // 2 MB
  float* po    = (float*)(ws + (1u << 19) + (3u << 21));       // 1024*4096*4 = 16 MB
  float* pml   = (float*)(ws + (1u << 19) + (3u << 21) + (1u << 24)); // 512 KB

  prep_w<<<(3 * DH * CEMB + 255) / 256, 256, 0, stream>>>(Wq, Wk, Wv, wt);
  qkv_gemm<<<dim3(512), 256, 0, stream>>>(x, wt, fc, fs, q_ws, k_ws, vt_ws);
  attn_partial<<<dim3(64, NB, NCHUNK), 256, 0, stream>>>(q_ws, k_ws, vt_ws, po, pml);
  attn_combine<<<dim3((NB * TSEQ * DH) / 256), 256, 0, stream>>>(po, pml, out);
}

// Round 8
// 170.050 us; speedup vs baseline: 1.3721x; 1.0608x over previous
//
#include <hip/hip_runtime.h>
#include <hip/hip_bf16.h>
#include <stdint.h>

// Problem constants (fixed by the reference)
#define TSEQ 4096
#define CEMB 1024
#define DH   64
#define NB   4
#define NCHUNK 4      // KV-split factor per q-tile (flash-decoding style)

typedef __attribute__((ext_vector_type(8))) short bf16x8;  // 8 bf16 (4 VGPRs) MFMA frag
typedef __attribute__((ext_vector_type(4))) float f32x4;   // MFMA accum frag
typedef __attribute__((ext_vector_type(4))) float f4;
typedef unsigned short u16;

// fp32 -> bf16 (compiler-generated convert; m240: don't hand-write cvt)
__device__ __forceinline__ u16 f2bf(float f) {
  __hip_bfloat16 h = __float2bfloat16(f);
  return *(u16*)&h;
}

// XOR-swizzled byte offset inside an LDS tile with 128-byte rows (64 bf16/row).
__device__ __forceinline__ int swz(int row, int colbyte) {
  return row * 128 + (colbyte ^ ((row & 7) << 4));
}

// ---------------------------------------------------------------------------
// prep: W[1024][64] fp32 (q,k,v) -> wt[3*64][1024] bf16 (transposed).
// ---------------------------------------------------------------------------
__global__ void prep_w(const float* __restrict__ Wq, const float* __restrict__ Wk,
                       const float* __restrict__ Wv, u16* __restrict__ wt) {
  int idx = blockIdx.x * 256 + threadIdx.x;
  if (idx >= 3 * DH * CEMB) return;
  int m = idx >> 16;            // which matrix
  int r = idx & 65535;          // index into W (row-major [k][n])
  int k = r >> 6, n = r & 63;
  const float* W = (m == 0) ? Wq : (m == 1) ? Wk : Wv;
  wt[(size_t)m * 65536 + n * 1024 + k] = f2bf(W[r]);
}

// ---------------------------------------------------------------------------
// Fused QKV projection GEMM: C[32 x 192] = X[32 x 1024] @ Wt^T per block.
// BM=32 (grid 512), BK=64, 4 waves = 2 row-groups x 2 col-groups. Double-
// buffered LDS staging, issue-early/write-late. RoPE fused in epilogue;
// q pre-scaled by 0.125 (folded attention scale, exact in bf16);
// v stored transposed vt[b][d][t].
// ---------------------------------------------------------------------------
#define QKV_LOADX(K0) { \
    const float* s_ = x + (size_t)(m0 + xrow) * CEMB + (K0) + xc * 8; \
    xa = *(const f4*)s_; xb = *(const f4*)(s_ + 4); }
#define QKV_LOADW(K0) \
    _Pragma("unroll") for (int it = 0; it < 6; ++it) { \
      int gg = it * 256 + tid; \
      wv[it] = *(const bf16x8*)(wt + (size_t)(gg >> 3) * CEMB + (K0) + (gg & 7) * 8); }
#define QKV_STORE(BUF) { \
    bf16x8 xv_; \
    xv_[0] = (short)f2bf(xa[0]); xv_[1] = (short)f2bf(xa[1]); \
    xv_[2] = (short)f2bf(xa[2]); xv_[3] = (short)f2bf(xa[3]); \
    xv_[4] = (short)f2bf(xb[0]); xv_[5] = (short)f2bf(xb[1]); \
    xv_[6] = (short)f2bf(xb[2]); xv_[7] = (short)f2bf(xb[3]); \
    *(bf16x8*)((char*)xs[BUF] + swz(xrow, xc << 4)) = xv_; \
    _Pragma("unroll") for (int it = 0; it < 6; ++it) { \
      int gg = it * 256 + tid; \
      *(bf16x8*)((char*)wsh[BUF] + swz(gg >> 3, (gg & 7) << 4)) = wv[it]; } }

__launch_bounds__(256)
__global__ void qkv_gemm(const float* __restrict__ x, const u16* __restrict__ wt,
                         const float* __restrict__ fc, const float* __restrict__ fs,
                         u16* __restrict__ q_ws, u16* __restrict__ k_ws,
                         u16* __restrict__ vt_ws) {
  __shared__ __align__(16) u16 xs[2][32 * 64];    //  8 KB
  __shared__ __align__(16) u16 wsh[2][192 * 64];  // 48 KB

  const int tid  = threadIdx.x;
  const int lane = tid & 63;
  const int w    = tid >> 6;
  const int l15  = lane & 15;
  const int lhi  = lane >> 4;
  const int rg   = w & 1;              // row-group (16 rows)
  const int cg   = w >> 1;             // col-group (96 cols)
  const int m0   = blockIdx.x * 32;
  const int xrow = tid >> 3, xc = tid & 7;   // X staging granule

  const f32x4 z4 = {0.f, 0.f, 0.f, 0.f};
  f32x4 acc[6];
#pragma unroll
  for (int j = 0; j < 6; ++j) acc[j] = z4;

  f4 xa, xb;
  bf16x8 wv[6];

  // prologue: stage k0 = 0 into buffer 0
  QKV_LOADX(0)
  QKV_LOADW(0)
  QKV_STORE(0)
  __syncthreads();

  for (int ks = 0; ks < CEMB / 64; ++ks) {
    const int cur  = ks & 1;
    const bool more = (ks + 1 < CEMB / 64);
    if (more) {                       // issue next tile's loads EARLY
      QKV_LOADX((ks + 1) * 64)
      QKV_LOADW((ks + 1) * 64)
    }
    // compute on current buffer: 12 MFMA per wave
#pragma unroll
    for (int kk = 0; kk < 2; ++kk) {
      bf16x8 af = *(const bf16x8*)((char*)xs[cur] + swz(rg * 16 + l15, (kk * 32 + lhi * 8) * 2));
#pragma unroll
      for (int nc = 0; nc < 6; ++nc) {
        bf16x8 bfr = *(const bf16x8*)((char*)wsh[cur] + swz(cg * 96 + nc * 16 + l15, (kk * 32 + lhi * 8) * 2));
        acc[nc] = __builtin_amdgcn_mfma_f32_16x16x32_bf16(af, bfr, acc[nc], 0, 0, 0);
      }
    }
    if (more) QKV_STORE(cur ^ 1)      // write LATE (latency hidden under MFMA)
    __syncthreads();
  }

  // epilogue: D row = (lane>>4)*4 + r, col = lane&15
#pragma unroll
  for (int nc = 0; nc < 6; ++nc) {
    int gcol = cg * 96 + nc * 16 + l15;   // 0..191
    int mat  = gcol >> 6;                 // 0=q 1=k 2=v
    int col  = gcol & 63;                 // head dim
#pragma unroll
    for (int r = 0; r < 4; ++r) {
      float v = acc[nc][r];
      float o = __shfl_xor(v, 1);         // RoPE pair partner (adjacent col)
      int row = m0 + rg * 16 + lhi * 4 + r;
      int b = row >> 12, t = row & 4095;
      if (mat == 2) {
        vt_ws[((size_t)(b * DH + col)) * TSEQ + t] = f2bf(v);
      } else {
        int p = col >> 1;
        float cv = fc[t * 32 + p], sv = fs[t * 32 + p];
        float outv = ((col & 1) == 0) ? (v * cv - o * sv)   // real part
                                      : (o * sv + v * cv);  // imag part
        if (mat == 0) outv *= 0.125f;     // fold attention scale into q (pow2, exact)
        u16* dst = (mat == 0) ? q_ws : k_ws;
        dst[(size_t)row * DH + col] = f2bf(outv);
      }
    }
  }
}

// ---------------------------------------------------------------------------
// Flash attention partials, causal, KV-chunked. QBLK=64 (4 waves x 16 rows),
// KVBLK=64, single-buffered LDS (24 KB -> 6 blocks/CU), issue-early loads.
// Diagonal-only masking, defer-max (THR=8), deferred cross-lane l-reduce,
// setprio around MFMA. Block (qt,b,c) -> partial (O f32, m, l).
// ---------------------------------------------------------------------------
#define ATT_LOADKV(KV0) \
    _Pragma("unroll") for (int it = 0; it < 2; ++it) { \
      int gg = it * 256 + tid, row_ = gg >> 3, cc_ = gg & 7; \
      kreg[it] = *(const bf16x8*)(kb + (size_t)((KV0) + row_) * DH + cc_ * 8); \
      vreg[it] = *(const bf16x8*)(vb + (size_t)row_ * TSEQ + (KV0) + cc_ * 8); }
#define ATT_WRITEKV \
    _Pragma("unroll") for (int it = 0; it < 2; ++it) { \
      int gg = it * 256 + tid, row_ = gg >> 3, cc_ = gg & 7; \
      *(bf16x8*)((char*)kt + swz(row_, cc_ << 4)) = kreg[it]; \
      *(bf16x8*)((char*)vts + swz(row_, cc_ << 4)) = vreg[it]; }

__launch_bounds__(256)
__global__ void attn_partial(const u16* __restrict__ q_ws, const u16* __restrict__ k_ws,
                             const u16* __restrict__ vt_ws, float* __restrict__ po,
                             float* __restrict__ pml) {
  const int qt = blockIdx.x;
  const int b  = blockIdx.y;
  const int c  = blockIdx.z;

  const int ntiles = qt + 1;                    // causal KV-tiles for this qtile
  const int cnt    = (ntiles + NCHUNK - 1) / NCHUNK;
  const int t0     = c * cnt;
  if (t0 >= ntiles) return;                     // dead chunk (uniform exit, pre-barrier)
  const int t1     = min(t0 + cnt, ntiles);

  __shared__ __align__(16) u16 kt[64 * 64];      // K tile, swizzled (8 KB)
  __shared__ __align__(16) u16 vts[64 * 64];     // V^T tile, swizzled (8 KB)
  __shared__ __align__(16) u16 pt2[4 * 16 * 64]; // per-wave P, swizzled (8 KB)

  const int tid  = threadIdx.x;
  const int lane = tid & 63;
  const int w    = tid >> 6;
  const int l15  = lane & 15;
  const int lhi  = lane >> 4;
  const int q0   = qt * 64;

  const u16* qb = q_ws + (size_t)b * TSEQ * DH;
  const u16* kb = k_ws + (size_t)b * TSEQ * DH;
  const u16* vb = vt_ws + (size_t)b * DH * TSEQ;
  char* ptw = (char*)pt2 + w * 2048;            // this wave's P region

  // Q fragments (A operand, rows = this wave's 16 q-rows); q pre-scaled by 0.125
  bf16x8 aq[2];
  {
    int qrow = q0 + w * 16 + l15;
#pragma unroll
    for (int kk = 0; kk < 2; ++kk)
      aq[kk] = *(const bf16x8*)(qb + (size_t)qrow * DH + kk * 32 + lhi * 8);
  }

  const f32x4 z4 = {0.f, 0.f, 0.f, 0.f};
  f32x4 oacc[4] = {z4, z4, z4, z4};
  float m_r[4], l_p[4];                         // l_p = per-LANE partial sum
#pragma unroll
  for (int r = 0; r < 4; ++r) { m_r[r] = -1e30f; l_p[r] = 0.f; }

  const int myqbase = q0 + w * 16 + lhi * 4;    // + r = this lane's q rows

  bf16x8 kreg[2], vreg[2];

  for (int kv = t0; kv < t1; ++kv) {
    const int kv0 = kv * 64;
    ATT_LOADKV(kv0)                   // issue loads; latency hides under barrier
    __syncthreads();                  // all waves done reading previous tile
    ATT_WRITEKV
    __syncthreads();

    // ---- S = Q K^T (16 x 64 per wave), scale pre-folded into q ----
    f32x4 sacc[4] = {z4, z4, z4, z4};
    __builtin_amdgcn_s_setprio(1);
#pragma unroll
    for (int kk = 0; kk < 2; ++kk) {
#pragma unroll
      for (int cb = 0; cb < 4; ++cb) {
        bf16x8 bk = *(const bf16x8*)((char*)kt + swz(cb * 16 + l15, (kk * 32 + lhi * 8) * 2));
        sacc[cb] = __builtin_amdgcn_mfma_f32_16x16x32_bf16(aq[kk], bk, sacc[cb], 0, 0, 0);
      }
    }
    __builtin_amdgcn_s_setprio(0);

    // ---- causal mask: DIAGONAL TILE ONLY (interior tiles fully unmasked) ----
    if (kv0 == q0) {
#pragma unroll
      for (int cb = 0; cb < 4; ++cb)
#pragma unroll
        for (int r = 0; r < 4; ++r) {
          int ki = kv0 + cb * 16 + l15;
          int qi = myqbase + r;
          if (ki > qi) sacc[cb][r] = -1e30f;
        }
    }
    // ---- row max (uniform across each 16-lane row group after reduce) ----
    float mx[4];
#pragma unroll
    for (int r = 0; r < 4; ++r)
      mx[r] = fmaxf(fmaxf(sacc[0][r], sacc[1][r]), fmaxf(sacc[2][r], sacc[3][r]));
#pragma unroll
    for (int s = 1; s <= 8; s <<= 1)
#pragma unroll
      for (int r = 0; r < 4; ++r) mx[r] = fmaxf(mx[r], __shfl_xor(mx[r], s));
    // ---- defer-max: skip rescale unless max grew by > 8 ----
    bool skip = true;
#pragma unroll
    for (int r = 0; r < 4; ++r) skip = skip && (mx[r] <= m_r[r] + 8.f);
    if (!__all(skip)) {
#pragma unroll
      for (int r = 0; r < 4; ++r) {
        float mn = fmaxf(m_r[r], mx[r]);
        float fac = __expf(m_r[r] - mn);
        m_r[r] = mn;
        l_p[r] *= fac;
#pragma unroll
        for (int nc = 0; nc < 4; ++nc) oacc[nc][r] *= fac;
      }
    }
    // ---- P = exp(S - m), per-lane l accumulation, P -> LDS (bf16) ----
#pragma unroll
    for (int cb = 0; cb < 4; ++cb)
#pragma unroll
      for (int r = 0; r < 4; ++r) {
        float p = __expf(sacc[cb][r] - m_r[r]);
        l_p[r] += p;
        *(u16*)(ptw + swz(lhi * 4 + r, (cb * 16 + l15) * 2)) = f2bf(p);
      }
    bf16x8 ap[2];
#pragma unroll
    for (int kk = 0; kk < 2; ++kk)
      ap[kk] = *(const bf16x8*)(ptw + swz(l15, (kk * 32 + lhi * 8) * 2));
    // ---- O += P V ----
    __builtin_amdgcn_s_setprio(1);
#pragma unroll
    for (int kk = 0; kk < 2; ++kk)
#pragma unroll
      for (int nc = 0; nc < 4; ++nc) {
        bf16x8 bv = *(const bf16x8*)((char*)vts + swz(nc * 16 + l15, (kk * 32 + lhi * 8) * 2));
        oacc[nc] = __builtin_amdgcn_mfma_f32_16x16x32_bf16(ap[kk], bv, oacc[nc], 0, 0, 0);
      }
    __builtin_amdgcn_s_setprio(0);
  }

  // ---- deferred cross-lane l reduction (once per kernel, not per step) ----
#pragma unroll
  for (int s = 1; s <= 8; s <<= 1)
#pragma unroll
    for (int r = 0; r < 4; ++r) l_p[r] += __shfl_xor(l_p[r], s);

  // write partial: O (no div), m, l
  const int slot = ((b * 64 + qt) * NCHUNK + c);
  float* o_out = po + (size_t)slot * (64 * 64);
#pragma unroll
  for (int nc = 0; nc < 4; ++nc)
#pragma unroll
    for (int r = 0; r < 4; ++r) {
      int rloc = w * 16 + lhi * 4 + r;
      o_out[rloc * 64 + nc * 16 + l15] = oacc[nc][r];
    }
#pragma unroll
  for (int r = 0; r < 4; ++r) {
    if (l15 == 0) {                        // one writer per row
      int rloc = w * 16 + lhi * 4 + r;
      pml[(size_t)slot * 128 + rloc]      = m_r[r];
      pml[(size_t)slot * 128 + 64 + rloc] = l_p[r];
    }
  }
}

// ---------------------------------------------------------------------------
// Combine partials: out[b][t][d] = sum_c e^{m_c-M} O_c[d] / sum_c e^{m_c-M} l_c
// ---------------------------------------------------------------------------
__launch_bounds__(256)
__global__ void attn_combine(const float* __restrict__ po, const float* __restrict__ pml,
                             float* __restrict__ out) {
  int idx = blockIdx.x * 256 + threadIdx.x;    // idx over B*T*DH = 1M
  int d   = idx & 63;
  int t   = (idx >> 6) & 4095;
  int b   = idx >> 18;
  int qt  = t >> 6;
  int rloc = t & 63;
  int ntiles = qt + 1;
  int cnt = (ntiles + NCHUNK - 1) / NCHUNK;

  float m_c[NCHUNK], l_c[NCHUNK], o_c[NCHUNK];
  float M = -1e30f;
#pragma unroll
  for (int c = 0; c < NCHUNK; ++c) {
    bool valid = (c * cnt < ntiles);
    int slot = ((b * 64 + qt) * NCHUNK + c);
    m_c[c] = valid ? pml[(size_t)slot * 128 + rloc]      : -1e30f;
    l_c[c] = valid ? pml[(size_t)slot * 128 + 64 + rloc] : 0.f;
    o_c[c] = valid ? po[(size_t)slot * (64 * 64) + rloc * 64 + d] : 0.f;
    M = fmaxf(M, m_c[c]);
  }
  float den = 0.f, num = 0.f;
#pragma unroll
  for (int c = 0; c < NCHUNK; ++c) {
    float e = __expf(m_c[c] - M);
    den += e * l_c[c];
    num += e * o_c[c];
  }
  out[idx] = num / den;
}

// ---------------------------------------------------------------------------
extern "C" void kernel_launch(void* const* d_in, const int* in_sizes, int n_in,
                              void* d_out, int out_size, void* d_ws, size_t ws_size,
                              hipStream_t stream) {
  const float* x  = (const float*)d_in[0];
  const float* Wq = (const float*)d_in[1];
  const float* Wk = (const float*)d_in[2];
  const float* Wv = (const float*)d_in[3];
  const float* fc = (const float*)d_in[4];
  const float* fs = (const float*)d_in[5];
  float* out = (float*)d_out;

  // workspace layout (~23 MB):
  char* ws = (char*)d_ws;
  u16*   wt    = (u16*)(ws);                                   // 384 KB (pad 512K)
  u16*   q_ws  = (u16*)(ws + (1u << 19));                      // 2 MB
  u16*   k_ws  = (u16*)(ws + (1u << 19) + (1u << 21));         // 2 MB
  u16*   vt_ws = (u16*)(ws + (1u << 19) + (2u << 21));         // 2 MB
  float* po    = (float*)(ws + (1u << 19) + (3u << 21));       // 1024*4096*4 = 16 MB
  float* pml   = (float*)(ws + (1u << 19) + (3u << 21) + (1u << 24)); // 512 KB

  prep_w<<<(3 * DH * CEMB + 255) / 256, 256, 0, stream>>>(Wq, Wk, Wv, wt);
  qkv_gemm<<<dim3(512), 256, 0, stream>>>(x, wt, fc, fs, q_ws, k_ws, vt_ws);
  attn_partial<<<dim3(64, NB, NCHUNK), 256, 0, stream>>>(q_ws, k_ws, vt_ws, po, pml);
  attn_combine<<<dim3((NB * TSEQ * DH) / 256), 256, 0, stream>>>(po, pml, out);
}